// Round 9
// baseline (845.345 us; speedup 1.0000x reference)
//
#include <hip/hip_runtime.h>
#include <hip/hip_bf16.h>
#include <hip/hip_cooperative_groups.h>

namespace cg = cooperative_groups;

// GCN link-prediction: 2x GCNConv(128->128) + edge dot scoring.
// Round 21: cooperative tail fusion. The serial chain {agg1 -> gemm2 ->
// agg2 -> score} (4 dispatches, 3 gaps + 3 kernel ramps) becomes ONE
// cooperative kernel with 3 grid.sync()s. To keep aggregate at FULL
// occupancy inside the mono-kernel: __launch_bounds__(256,8) (<=64 VGPR)
// and gemm2 as column-half tiles (64 cols, 16KB LDS, acc 32 regs).
// Grid sized via occupancy query (static-cached); fallback = R20's four
// separate launches if coop unavailable. L0/L1 unchanged from R20.
// LESSONS BANKED:
// - aggregate gather: pinned at ~3.65 TB/s random-64B fabric floor; FETCH
//   181MB invariant; issue-order micro-tuning is noise (R17).
// - never fuse latency-bound gather with reg/LDS-heavy MFMA in the SAME
//   blocks (R10); phase-split in one kernel is different: occupancy is
//   governed by max(VGPR,LDS) across phases - keep both low.
// - never read MFMA B-frags strided from global, incl. staging (R11/R16).
// - partial-line scatter = write-allocate amplification (R13, R18).
// - CSR via LDS counting sort >> 1M global atomics (R14: -57us).
// - launch gap ~2-4us each: minimize dispatch count (R18/R19/R20).

#define N_NODES 100000
#define N_EDGES 1000000
#define N_LABEL 200000
#define D_FEAT 128
#define BM 128

#define NB 782        // coarse buckets: ceil(100000/128) nodes each
#define BCAP 2048     // pass2 LDS capacity per bucket (mean 1279, +6sig ~1500)
#define P1_EPT 16     // pass1 edges per thread
#define P1_BLOCKS 245 // ceil(1e6/4096)
#define G_GEMM 782    // ceil(100000/128)
#define G_CONV 128    // W1+W2 conversion blocks (32768 elems / 256)
#define AGG_VB 12500  // aggregate virtual blocks (8 nodes each)
#define SCORE_VB 12500

typedef short bf16x8 __attribute__((ext_vector_type(8)));
typedef float f32x4 __attribute__((ext_vector_type(4)));

// ---- bf16 helpers (RNE) ----
__device__ inline unsigned int f2bf(float x) {
    unsigned int u = __float_as_uint(x);
    return (u + 0x7FFFu + ((u >> 16) & 1u)) >> 16;
}
__device__ inline unsigned int bf16pack(float a, float b) {
    return f2bf(a) | (f2bf(b) << 16);
}
__device__ inline float bflo(unsigned int u) { return __uint_as_float(u << 16); }
__device__ inline float bfhi(unsigned int u) { return __uint_as_float(u & 0xFFFF0000u); }

// ---------------- L0: {w2bf || pass1 (scatter-free)} ------------------------
__global__ __launch_bounds__(256) void w2bf_pass1(
    const float* __restrict__ W1, const float* __restrict__ W2,
    unsigned short* __restrict__ Wt1, unsigned short* __restrict__ Wt2,
    const int* __restrict__ src, const int* __restrict__ dst,
    unsigned int* __restrict__ temp, int* __restrict__ bofs) {
    __shared__ __align__(16) unsigned int S[4096 + 1024 + 256];  // 21.5 KB
    int b = blockIdx.x, t = threadIdx.x;
    if (b < G_CONV) {
        int i = b * 256 + t;  // 0..32767
        const float* W = (i < 16384) ? W1 : W2;
        unsigned short* Wt = (i < 16384) ? Wt1 : Wt2;
        int j = i & 16383;
        int n = j >> 7, k = j & 127;
        Wt[j] = (unsigned short)f2bf(W[(size_t)k * 128 + n]);
        return;
    }
    b -= G_CONV;
    unsigned int* ed16 = S;            // 4096 u32 (16 KB)
    int* hist = (int*)(ed16 + 4096);   // 1024 ints (bins padded)
    int* red = hist + 1024;            // 256

    for (int i = t; i < 1024; i += 256) hist[i] = 0;
    __syncthreads();

    int se[P1_EPT], de[P1_EPT], rk[P1_EPT];
    int e0 = b * 4096 + t;
#pragma unroll
    for (int j = 0; j < P1_EPT; ++j) {
        int e = e0 + j * 256;
        if (e < N_EDGES) {
            se[j] = src[e];
            de[j] = dst[e];
            rk[j] = atomicAdd(&hist[de[j] >> 7], 1);
        }
    }
    __syncthreads();

    // exclusive scan over 1024 bins: thread t owns bins 4t..4t+3
    int c0 = hist[4 * t], c1 = hist[4 * t + 1], c2 = hist[4 * t + 2], c3 = hist[4 * t + 3];
    int s = c0 + c1 + c2 + c3;
    red[t] = s;
    __syncthreads();
    for (int off = 1; off < 256; off <<= 1) {
        int a = (t >= off) ? red[t - off] : 0;
        __syncthreads();
        red[t] += a;
        __syncthreads();
    }
    int excl = red[t] - s;
    hist[4 * t] = excl;
    hist[4 * t + 1] = excl + c0;
    hist[4 * t + 2] = excl + c0 + c1;
    hist[4 * t + 3] = excl + c0 + c1 + c2;
    __syncthreads();

    // scatter records into LDS (bucket-sorted within block)
#pragma unroll
    for (int j = 0; j < P1_EPT; ++j) {
        int e = e0 + j * 256;
        if (e < N_EDGES) {
            int pos = hist[de[j] >> 7] + rk[j];
            ed16[pos] = (unsigned int)(((de[j] & 127) << 17) | se[j]);
        }
    }
    __syncthreads();

    // coalesced dump + bofs
#pragma unroll
    for (int i = 0; i < 4; ++i)
        ((uint4*)temp)[(size_t)b * 1024 + i * 256 + t] = ((uint4*)ed16)[i * 256 + t];
    for (int j = t; j < NB; j += 256) bofs[b * (NB + 1) + j] = hist[j];
    if (t == 0) {
        int cnt = N_EDGES - b * 4096;
        if (cnt > 4096) cnt = 4096;
        bofs[b * (NB + 1) + NB] = cnt;
    }
}

// ---------------- MFMA GEMM body (full 128-col), LDS-staged bf16 W ---------
template <bool BF16_IN>
__device__ __forceinline__ void gemm_body(const void* __restrict__ Xv,
                                          const unsigned short* __restrict__ Wt,
                                          unsigned int* __restrict__ Y,
                                          int nrows, int bid, short* Ws) {
    int t = threadIdx.x;
#pragma unroll
    for (int i = 0; i < 8; ++i) {
        int c = i * 256 + t;
        int n = c >> 4, q = c & 15;
        uint4 v = *(const uint4*)&Wt[(size_t)n * 128 + q * 8];
        *(uint4*)&Ws[n * 128 + ((q ^ (n & 15)) << 3)] = v;
    }
    __syncthreads();

    int wv = t >> 6;
    int lane = t & 63, l16 = lane & 15, quad = lane >> 4;
    int rbase = bid * BM + wv * 32;

    f32x4 acc[2][8];
#pragma unroll
    for (int rt = 0; rt < 2; ++rt)
#pragma unroll
        for (int nt = 0; nt < 8; ++nt) acc[rt][nt] = (f32x4){0.f, 0.f, 0.f, 0.f};

#pragma unroll
    for (int kb = 0; kb < 4; ++kb) {
        bf16x8 af[2];
#pragma unroll
        for (int rt = 0; rt < 2; ++rt) {
            int row = rbase + rt * 16 + l16;
            if (row > nrows - 1) row = nrows - 1;
            if constexpr (BF16_IN) {
                const unsigned int* Xb = (const unsigned int*)Xv;
                af[rt] = *(const bf16x8*)&Xb[(size_t)row * 64 + kb * 16 + quad * 4];
            } else {
                const float* X = (const float*)Xv;
                float4 fa = ((const float4*)X)[(size_t)row * 32 + kb * 8 + quad * 2];
                float4 fb = ((const float4*)X)[(size_t)row * 32 + kb * 8 + quad * 2 + 1];
                union { uint4 u; bf16x8 v; } cv;
                cv.u.x = bf16pack(fa.x, fa.y);
                cv.u.y = bf16pack(fa.z, fa.w);
                cv.u.z = bf16pack(fb.x, fb.y);
                cv.u.w = bf16pack(fb.z, fb.w);
                af[rt] = cv.v;
            }
        }
        bf16x8 bfr[8];
#pragma unroll
        for (int nt = 0; nt < 8; ++nt) {
            int n = nt * 16 + l16;
            bfr[nt] = *(const bf16x8*)&Ws[n * 128 + (((kb * 4 + quad) ^ l16) << 3)];
        }
#pragma unroll
        for (int rt = 0; rt < 2; ++rt)
#pragma unroll
            for (int nt = 0; nt < 8; ++nt)
                acc[rt][nt] = __builtin_amdgcn_mfma_f32_16x16x32_bf16(
                    af[rt], bfr[nt], acc[rt][nt], 0, 0, 0);
    }

    short* Ys = (short*)Y;
#pragma unroll
    for (int rt = 0; rt < 2; ++rt)
#pragma unroll
        for (int reg = 0; reg < 4; ++reg) {
            int row = rbase + rt * 16 + quad * 4 + reg;
            if (row < nrows) {
#pragma unroll
                for (int nt = 0; nt < 8; ++nt)
                    Ys[(size_t)row * 128 + nt * 16 + l16] = (short)f2bf(acc[rt][nt][reg]);
            }
        }
}

// standalone GEMM (fallback layer 2, bf16 input)
__global__ __launch_bounds__(256) void gemm128_mfma_bf16(const unsigned int* __restrict__ Xb,
                                                         const unsigned short* __restrict__ Wt,
                                                         unsigned int* __restrict__ Y,
                                                         int nrows) {
    __shared__ __align__(16) short Ws[128 * 128];
    gemm_body<true>(Xb, Wt, Y, nrows, blockIdx.x, Ws);
}

// ---------------- L1: {gemm1 (f32 input) || pass2 fine sort} ----------------
__global__ __launch_bounds__(256) void fused_gemm1_pass2(
    const float* __restrict__ feat, const unsigned short* __restrict__ wt1,
    unsigned int* __restrict__ Hb,
    const unsigned int* __restrict__ temp, const int* __restrict__ bofs,
    int* __restrict__ row_ptr, float* __restrict__ dinv,
    int* __restrict__ packed) {
    __shared__ __align__(16) short Ws[128 * 128];  // gemm tile / pass2 union
    int b = blockIdx.x, t = threadIdx.x;
    if (b < G_GEMM) {
        gemm_body<false>(feat, wt1, Hb, N_NODES, b, Ws);
        return;
    }
    int k = b - G_GEMM;
    unsigned int* ed = (unsigned int*)Ws;  // BCAP u32 (8 KB)
    int* hist = (int*)(ed + BCAP);         // 128
    int* rp = hist + 128;                  // 128
    int* cur = rp + 128;                   // 128
    int* sc2 = cur + 128;                  // 128
    int* red = sc2 + 128;                  // 256
    int* sc = red + 256;                   // 256

    int s_t = 0, len = 0;
    if (t < P1_BLOCKS) {
        s_t = bofs[t * (NB + 1) + k];
        len = bofs[t * (NB + 1) + k + 1] - s_t;
    }
    // gbase = sum_b s_b
    red[t] = s_t;
    __syncthreads();
    for (int off = 128; off > 0; off >>= 1) {
        if (t < off) red[t] += red[t + off];
        __syncthreads();
    }
    int gbase = red[0];
    __syncthreads();
    // dloc: exclusive scan of segment lengths
    sc[t] = len;
    __syncthreads();
    for (int off = 1; off < 256; off <<= 1) {
        int a = (t >= off) ? sc[t - off] : 0;
        __syncthreads();
        sc[t] += a;
        __syncthreads();
    }
    int dloc = sc[t] - len;
    int nk = sc[255];
    if (nk > BCAP) nk = BCAP;

    if (t < 128) { hist[t] = 0; cur[t] = 0; }
    __syncthreads();
    // gather segments into LDS
    for (int i = 0; i < len; ++i) {
        int d = dloc + i;
        if (d < BCAP) ed[d] = temp[(size_t)t * 4096 + s_t + i];
    }
    __syncthreads();
    for (int i = t; i < nk; i += 256) atomicAdd(&hist[ed[i] >> 17], 1);
    __syncthreads();

    // exclusive scan over 128 bins
    if (t < 128) sc2[t] = hist[t];
    __syncthreads();
    for (int off = 1; off < 128; off <<= 1) {
        int a = (t < 128 && t >= off) ? sc2[t - off] : 0;
        __syncthreads();
        if (t < 128) sc2[t] += a;
        __syncthreads();
    }
    if (t < 128) {
        rp[t] = sc2[t] - hist[t];
        int n = k * 128 + t;
        if (n < N_NODES) {
            row_ptr[n] = gbase + rp[t];
            dinv[n] = rsqrtf((float)(hist[t] + 1));  // +1 self-loop
        }
    }
    if (k == NB - 1 && t == 0) row_ptr[N_NODES] = N_EDGES;
    __syncthreads();

    for (int i = t; i < nk; i += 256) {
        unsigned int v = ed[i];
        int dl = v >> 17;
        int r = atomicAdd(&cur[dl], 1);
        packed[gbase + rp[dl] + r] = (int)(v & 0x1FFFF);
    }
}

// ---------------- aggregate body (vb-parameterized) -------------------------
// packed = src only (4B/edge). x[v] = dv*(dv*H[v] + sum_s dinv[s]*H[s]) + b.
template <bool RELU>
__device__ __forceinline__ void agg_dev(int vb, const unsigned int* __restrict__ Hb,
                                        const int* __restrict__ packed,
                                        const int* __restrict__ row_ptr,
                                        const float* __restrict__ dinv,
                                        const float* __restrict__ bias,
                                        unsigned int* __restrict__ Xb) {
    int v0 = vb * 8 + (threadIdx.x >> 6) * 2;
    int v1 = v0 + 1;
    int lane = threadIdx.x & 63;
    if (v0 >= N_NODES) return;  // no barriers below: safe in device fn
    bool h1 = (v1 < N_NODES);

    int st0 = row_ptr[v0], en0 = row_ptr[v0 + 1];
    int st1 = h1 ? row_ptr[v1] : 0, en1 = h1 ? row_ptr[v1 + 1] : 0;
    float dv0 = dinv[v0];
    float dv1 = h1 ? dinv[v1] : 0.f;

    unsigned int su0 = Hb[(size_t)v0 * 64 + lane];
    float a0 = dv0 * bflo(su0), a1 = dv0 * bfhi(su0);
    unsigned int su1 = h1 ? Hb[(size_t)v1 * 64 + lane] : 0u;
    float b0 = dv1 * bflo(su1), b1 = dv1 * bfhi(su1);

    // meta prefetch for first chunk
    int p = 0;
    if (lane < 32) {
        if (st0 + lane < en0) p = packed[st0 + lane];
    } else {
        if (st1 + lane - 32 < en1) p = packed[st1 + lane - 32];
    }

    for (int c0 = st0, c1 = st1; c0 < en0 || c1 < en1; c0 += 32, c1 += 32) {
        int n0 = en0 - c0; n0 = n0 < 0 ? 0 : (n0 > 32 ? 32 : n0);
        int n1 = en1 - c1; n1 = n1 < 0 ? 0 : (n1 > 32 ? 32 : n1);
        bool act = (lane < 32) ? (lane < n0) : (lane - 32 < n1);
        float dld = dinv[p];          // p=0 for inactive lanes: safe addr
        float d = act ? dld : 0.f;    // masked after load

        int nmax = n0 > n1 ? n0 : n1;
        int pn = 0;
        bool pref = false;
        for (int j = 0; j < nmax; j += 8) {
            int sA[8], sB[8];
#pragma unroll
            for (int q = 0; q < 8; ++q) {
                sA[q] = __shfl(p, j + q);
                sB[q] = __shfl(p, 32 + j + q);
            }
            unsigned int uA[8], uB[8];
#pragma unroll
            for (int q = 0; q < 8; ++q) {
                uA[q] = Hb[(size_t)sA[q] * 64 + lane];
                uB[q] = Hb[(size_t)sB[q] * 64 + lane];
            }
            if (!pref) {  // prefetch next-chunk meta under the first gathers
                pref = true;
                if (lane < 32) {
                    if (c0 + 32 + lane < en0) pn = packed[c0 + 32 + lane];
                } else {
                    if (c1 + lane < en1) pn = packed[c1 + lane];
                }
            }
            float dA[8], dB[8];
#pragma unroll
            for (int q = 0; q < 8; ++q) {
                dA[q] = __shfl(d, j + q);
                dB[q] = __shfl(d, 32 + j + q);
            }
#pragma unroll
            for (int q = 0; q < 8; ++q) {
                a0 = fmaf(dA[q], bflo(uA[q]), a0);
                a1 = fmaf(dA[q], bfhi(uA[q]), a1);
                b0 = fmaf(dB[q], bflo(uB[q]), b0);
                b1 = fmaf(dB[q], bfhi(uB[q]), b1);
            }
        }
        p = pn;
    }

    float2 bb = ((const float2*)bias)[lane];
    a0 = fmaf(a0, dv0, bb.x);
    a1 = fmaf(a1, dv0, bb.y);
    b0 = fmaf(b0, dv1, bb.x);
    b1 = fmaf(b1, dv1, bb.y);
    if (RELU) {
        a0 = fmaxf(a0, 0.f);
        a1 = fmaxf(a1, 0.f);
        b0 = fmaxf(b0, 0.f);
        b1 = fmaxf(b1, 0.f);
    }
    Xb[(size_t)v0 * 64 + lane] = bf16pack(a0, a1);
    if (h1) Xb[(size_t)v1 * 64 + lane] = bf16pack(b0, b1);
}

// fallback wrapper
template <bool RELU>
__global__ __launch_bounds__(256) void aggregate(const unsigned int* __restrict__ Hb,
                                                 const int* __restrict__ packed,
                                                 const int* __restrict__ row_ptr,
                                                 const float* __restrict__ dinv,
                                                 const float* __restrict__ bias,
                                                 unsigned int* __restrict__ Xb) {
    agg_dev<RELU>(blockIdx.x, Hb, packed, row_ptr, dinv, bias, Xb);
}

// ---------------- score body (vb-parameterized) -----------------------------
__device__ __forceinline__ void score_dev(int vb, const int* __restrict__ ea,
                                          const int* __restrict__ eb,
                                          const unsigned int* __restrict__ Xb,
                                          float* __restrict__ out) {
    int wbase = (vb * 4 + (threadIdx.x >> 6)) * 4;
    int lane = threadIdx.x & 63;
    if (wbase >= N_LABEL) return;  // no barriers: safe
    int ne = N_LABEL - wbase;
    if (ne > 4) ne = 4;

    unsigned int ua[4], ub[4];
#pragma unroll
    for (int e = 0; e < 4; ++e)
        if (e < ne) {
            int ia = ea[wbase + e], ib = eb[wbase + e];
            ua[e] = Xb[(size_t)ia * 64 + lane];
            ub[e] = Xb[(size_t)ib * 64 + lane];
        }
#pragma unroll
    for (int e = 0; e < 4; ++e)
        if (e < ne) {
            float p = bflo(ua[e]) * bflo(ub[e]) + bfhi(ua[e]) * bfhi(ub[e]);
#pragma unroll
            for (int off = 32; off > 0; off >>= 1) p += __shfl_down(p, off);
            if (lane == 0) out[wbase + e] = p;
        }
}

// fallback wrapper
__global__ __launch_bounds__(256) void score_kernel(const int* __restrict__ ea,
                                                    const int* __restrict__ eb,
                                                    const unsigned int* __restrict__ Xb,
                                                    float* __restrict__ out) {
    score_dev(blockIdx.x, ea, eb, Xb, out);
}

// ---------------- gemm2 column-half tile (16KB LDS, acc 32 regs) ------------
// vb -> (row-block bid, col-half h). Block: 128 rows x 64 cols. Same swizzle
// and fragment math as gemm_body (n restricted to 0..63; n&15 == l16 holds).
__device__ __forceinline__ void gemm2half_dev(int vb, const unsigned int* __restrict__ Xb,
                                              const unsigned short* __restrict__ Wt,
                                              unsigned int* __restrict__ Y, short* Ws) {
    int bid = vb >> 1, h = vb & 1;
    int t = threadIdx.x;
#pragma unroll
    for (int i = 0; i < 4; ++i) {
        int c = i * 256 + t;        // 0..1023
        int n = c >> 4, q = c & 15; // n 0..63
        uint4 v = *(const uint4*)&Wt[(size_t)(h * 64 + n) * 128 + q * 8];
        *(uint4*)&Ws[n * 128 + ((q ^ (n & 15)) << 3)] = v;
    }
    __syncthreads();

    int wv = t >> 6;
    int lane = t & 63, l16 = lane & 15, quad = lane >> 4;
    int rbase = bid * BM + wv * 32;

    f32x4 acc[2][4];
#pragma unroll
    for (int rt = 0; rt < 2; ++rt)
#pragma unroll
        for (int nt = 0; nt < 4; ++nt) acc[rt][nt] = (f32x4){0.f, 0.f, 0.f, 0.f};

#pragma unroll
    for (int kb = 0; kb < 4; ++kb) {
        bf16x8 af[2];
#pragma unroll
        for (int rt = 0; rt < 2; ++rt) {
            int row = rbase + rt * 16 + l16;
            if (row > N_NODES - 1) row = N_NODES - 1;
            af[rt] = *(const bf16x8*)&Xb[(size_t)row * 64 + kb * 16 + quad * 4];
        }
        bf16x8 bfr[4];
#pragma unroll
        for (int nt = 0; nt < 4; ++nt) {
            int n = nt * 16 + l16;
            bfr[nt] = *(const bf16x8*)&Ws[n * 128 + (((kb * 4 + quad) ^ l16) << 3)];
        }
#pragma unroll
        for (int rt = 0; rt < 2; ++rt)
#pragma unroll
            for (int nt = 0; nt < 4; ++nt)
                acc[rt][nt] = __builtin_amdgcn_mfma_f32_16x16x32_bf16(
                    af[rt], bfr[nt], acc[rt][nt], 0, 0, 0);
    }
    __syncthreads();  // Ws reused by next vb iteration

    short* Ys = (short*)Y;
#pragma unroll
    for (int rt = 0; rt < 2; ++rt)
#pragma unroll
        for (int reg = 0; reg < 4; ++reg) {
            int row = rbase + rt * 16 + quad * 4 + reg;
            if (row < N_NODES) {
#pragma unroll
                for (int nt = 0; nt < 4; ++nt)
                    Ys[(size_t)row * 128 + h * 64 + nt * 16 + l16] =
                        (short)f2bf(acc[rt][nt][reg]);
            }
        }
}

// ---------------- cooperative tail: agg1 -> gemm2 -> agg2 -> score ----------
__global__ __launch_bounds__(256, 8) void tail_coop(
    unsigned int* __restrict__ Hb, const int* __restrict__ packed,
    const int* __restrict__ row_ptr, const float* __restrict__ dinv,
    const float* __restrict__ b1, unsigned int* __restrict__ Xb,
    const unsigned short* __restrict__ wt2, const float* __restrict__ b2,
    const int* __restrict__ la, const int* __restrict__ lb,
    float* __restrict__ out) {
    __shared__ __align__(16) short Ws[64 * 128];  // 16 KB (gemm2 phase only)
    cg::grid_group grid = cg::this_grid();
    int nb = gridDim.x;

    for (int vb = blockIdx.x; vb < AGG_VB; vb += nb)
        agg_dev<true>(vb, Hb, packed, row_ptr, dinv, b1, Xb);
    grid.sync();
    for (int vb = blockIdx.x; vb < 2 * G_GEMM; vb += nb)
        gemm2half_dev(vb, Xb, wt2, Hb, Ws);
    grid.sync();
    for (int vb = blockIdx.x; vb < AGG_VB; vb += nb)
        agg_dev<false>(vb, Hb, packed, row_ptr, dinv, b2, Xb);
    grid.sync();
    for (int vb = blockIdx.x; vb < SCORE_VB; vb += nb)
        score_dev(vb, la, lb, Xb, out);
}

extern "C" void kernel_launch(void* const* d_in, const int* in_sizes, int n_in,
                              void* d_out, int out_size, void* d_ws, size_t ws_size,
                              hipStream_t stream) {
    const float* feat = (const float*)d_in[0];
    const int* ei = (const int*)d_in[1];
    const int* eli = (const int*)d_in[2];
    const float* W1 = (const float*)d_in[3];
    const float* b1 = (const float*)d_in[4];
    const float* W2 = (const float*)d_in[5];
    const float* b2 = (const float*)d_in[6];
    float* out = (float*)d_out;

    const int* src = ei;
    const int* dst = ei + N_EDGES;
    const int* la = eli;
    const int* lb = eli + N_LABEL;

    int* row_ptr = (int*)d_ws;                                // N+4 ints
    float* dinv = (float*)(row_ptr + N_NODES + 4);            // N
    unsigned short* wt1 = (unsigned short*)(dinv + N_NODES);  // 16384 ushort
    unsigned short* wt2 = wt1 + 16384;                        // 16384 ushort
    int* packed = (int*)(wt2 + 16384);                        // E ints (4 MB)
    unsigned int* Hb = (unsigned int*)(packed + N_EDGES);     // N*64 uints
    unsigned int* Xb = Hb + (size_t)N_NODES * 64;             // N*64 uints
    // temp (block-major records, 4 MB) + bofs (245*783 ints) alias Xb
    unsigned int* temp = Xb;
    int* bofs = (int*)(temp + (size_t)P1_BLOCKS * 4096);

    const int TB = 256;
    int gGemm = (N_NODES + BM - 1) / BM;  // 782
    int gAgg = (N_NODES + 7) / 8;         // 12500
    int gScore = (N_LABEL + 15) / 16;     // 12500

    // coop grid: occupancy-query * CU count, static-cached (-1 = disabled)
    static int coop_grid = -2;
    if (coop_grid == -2) {
        int nb = 0;
        hipError_t e1 = hipOccupancyMaxActiveBlocksPerMultiprocessor(&nb, tail_coop, 256, 0);
        if (e1 != hipSuccess || nb < 1) {
            coop_grid = -1;
        } else {
            int dev = 0;
            hipGetDevice(&dev);
            hipDeviceProp_t prop;
            if (hipGetDeviceProperties(&prop, dev) != hipSuccess) {
                coop_grid = -1;
            } else {
                long g = (long)nb * prop.multiProcessorCount;
                coop_grid = (int)(g < AGG_VB ? g : AGG_VB);
            }
        }
    }

    // L0: w2bf || pass1 (both independent of everything)
    w2bf_pass1<<<G_CONV + P1_BLOCKS, TB, 0, stream>>>(W1, W2, wt1, wt2,
                                                      src, dst, temp, bofs);

    // L1: gemm1 || pass2 (gemm1 needs wt1 only; pass2 needs pass1 only)
    fused_gemm1_pass2<<<G_GEMM + NB, TB, 0, stream>>>(
        feat, wt1, Hb, temp, bofs, row_ptr, dinv, packed);

    // L2: cooperative tail {agg1 -> gemm2 -> agg2 -> score}
    bool coop_ok = false;
    if (coop_grid > 0) {
        void* cargs[11] = {(void*)&Hb,     (void*)&packed, (void*)&row_ptr,
                           (void*)&dinv,   (void*)&b1,     (void*)&Xb,
                           (void*)&wt2,    (void*)&b2,     (void*)&la,
                           (void*)&lb,     (void*)&out};
        coop_ok = (hipLaunchCooperativeKernel(tail_coop, dim3(coop_grid), dim3(TB),
                                              cargs, 0, stream) == hipSuccess);
    }
    if (!coop_ok) {
        // fallback: R20's proven 4-launch tail
        aggregate<true><<<gAgg, TB, 0, stream>>>(Hb, packed, row_ptr, dinv, b1, Xb);
        gemm128_mfma_bf16<<<gGemm, TB, 0, stream>>>(Xb, wt2, Hb, N_NODES);
        aggregate<false><<<gAgg, TB, 0, stream>>>(Hb, packed, row_ptr, dinv, b2, Xb);
        score_kernel<<<gScore, TB, 0, stream>>>(la, lb, Xb, out);
    }
}

// Round 10
// 605.721 us; speedup vs baseline: 1.3956x; 1.3956x over previous
//
#include <hip/hip_runtime.h>
#include <hip/hip_bf16.h>
#include <hip/hip_cooperative_groups.h>

namespace cg = cooperative_groups;

// GCN link-prediction: 2x GCNConv(128->128) + edge dot scoring.
// Round 22: R21's coop tail regressed 3x because __launch_bounds__(256,8)
// capped VGPR at 32 -> agg inner-loop arrays spilled to scratch (FETCH 724MB,
// WRITE 383MB, VALUBusy 5.5%). Fix: plain __launch_bounds__(256) - allocator
// picks ~70-90 VGPR (no spill), coop grid sized by occupancy query (~5-6
// blk/CU >= aggregate's natural 44% occupancy). Everything else = R21/R20.
// LESSONS BANKED:
// - NEVER set launch_bounds min-waves on kernels whose hot phase needs
//   register-resident MLP state; spill turns 78MB writes into 383MB (R21).
// - aggregate gather: pinned at ~3.65 TB/s random-64B fabric floor; FETCH
//   181MB invariant; issue-order micro-tuning is noise (R17).
// - never fuse latency-bound gather with reg/LDS-heavy MFMA in the SAME
//   blocks (R10); phase-split one-kernel is fine if VGPR/LDS stay low.
// - never read MFMA B-frags strided from global, incl. staging (R11/R16).
// - partial-line scatter = write-allocate amplification (R13, R18).
// - CSR via LDS counting sort >> 1M global atomics (R14: -57us).
// - launch gap ~2-4us each: minimize dispatch count (R18/R19/R20).

#define N_NODES 100000
#define N_EDGES 1000000
#define N_LABEL 200000
#define D_FEAT 128
#define BM 128

#define NB 782        // coarse buckets: ceil(100000/128) nodes each
#define BCAP 2048     // pass2 LDS capacity per bucket (mean 1279, +6sig ~1500)
#define P1_EPT 16     // pass1 edges per thread
#define P1_BLOCKS 245 // ceil(1e6/4096)
#define G_GEMM 782    // ceil(100000/128)
#define G_CONV 128    // W1+W2 conversion blocks (32768 elems / 256)
#define AGG_VB 12500  // aggregate virtual blocks (8 nodes each)
#define SCORE_VB 12500

typedef short bf16x8 __attribute__((ext_vector_type(8)));
typedef float f32x4 __attribute__((ext_vector_type(4)));

// ---- bf16 helpers (RNE) ----
__device__ inline unsigned int f2bf(float x) {
    unsigned int u = __float_as_uint(x);
    return (u + 0x7FFFu + ((u >> 16) & 1u)) >> 16;
}
__device__ inline unsigned int bf16pack(float a, float b) {
    return f2bf(a) | (f2bf(b) << 16);
}
__device__ inline float bflo(unsigned int u) { return __uint_as_float(u << 16); }
__device__ inline float bfhi(unsigned int u) { return __uint_as_float(u & 0xFFFF0000u); }

// ---------------- L0: {w2bf || pass1 (scatter-free)} ------------------------
__global__ __launch_bounds__(256) void w2bf_pass1(
    const float* __restrict__ W1, const float* __restrict__ W2,
    unsigned short* __restrict__ Wt1, unsigned short* __restrict__ Wt2,
    const int* __restrict__ src, const int* __restrict__ dst,
    unsigned int* __restrict__ temp, int* __restrict__ bofs) {
    __shared__ __align__(16) unsigned int S[4096 + 1024 + 256];  // 21.5 KB
    int b = blockIdx.x, t = threadIdx.x;
    if (b < G_CONV) {
        int i = b * 256 + t;  // 0..32767
        const float* W = (i < 16384) ? W1 : W2;
        unsigned short* Wt = (i < 16384) ? Wt1 : Wt2;
        int j = i & 16383;
        int n = j >> 7, k = j & 127;
        Wt[j] = (unsigned short)f2bf(W[(size_t)k * 128 + n]);
        return;
    }
    b -= G_CONV;
    unsigned int* ed16 = S;            // 4096 u32 (16 KB)
    int* hist = (int*)(ed16 + 4096);   // 1024 ints (bins padded)
    int* red = hist + 1024;            // 256

    for (int i = t; i < 1024; i += 256) hist[i] = 0;
    __syncthreads();

    int se[P1_EPT], de[P1_EPT], rk[P1_EPT];
    int e0 = b * 4096 + t;
#pragma unroll
    for (int j = 0; j < P1_EPT; ++j) {
        int e = e0 + j * 256;
        if (e < N_EDGES) {
            se[j] = src[e];
            de[j] = dst[e];
            rk[j] = atomicAdd(&hist[de[j] >> 7], 1);
        }
    }
    __syncthreads();

    // exclusive scan over 1024 bins: thread t owns bins 4t..4t+3
    int c0 = hist[4 * t], c1 = hist[4 * t + 1], c2 = hist[4 * t + 2], c3 = hist[4 * t + 3];
    int s = c0 + c1 + c2 + c3;
    red[t] = s;
    __syncthreads();
    for (int off = 1; off < 256; off <<= 1) {
        int a = (t >= off) ? red[t - off] : 0;
        __syncthreads();
        red[t] += a;
        __syncthreads();
    }
    int excl = red[t] - s;
    hist[4 * t] = excl;
    hist[4 * t + 1] = excl + c0;
    hist[4 * t + 2] = excl + c0 + c1;
    hist[4 * t + 3] = excl + c0 + c1 + c2;
    __syncthreads();

    // scatter records into LDS (bucket-sorted within block)
#pragma unroll
    for (int j = 0; j < P1_EPT; ++j) {
        int e = e0 + j * 256;
        if (e < N_EDGES) {
            int pos = hist[de[j] >> 7] + rk[j];
            ed16[pos] = (unsigned int)(((de[j] & 127) << 17) | se[j]);
        }
    }
    __syncthreads();

    // coalesced dump + bofs
#pragma unroll
    for (int i = 0; i < 4; ++i)
        ((uint4*)temp)[(size_t)b * 1024 + i * 256 + t] = ((uint4*)ed16)[i * 256 + t];
    for (int j = t; j < NB; j += 256) bofs[b * (NB + 1) + j] = hist[j];
    if (t == 0) {
        int cnt = N_EDGES - b * 4096;
        if (cnt > 4096) cnt = 4096;
        bofs[b * (NB + 1) + NB] = cnt;
    }
}

// ---------------- MFMA GEMM body (full 128-col), LDS-staged bf16 W ---------
template <bool BF16_IN>
__device__ __forceinline__ void gemm_body(const void* __restrict__ Xv,
                                          const unsigned short* __restrict__ Wt,
                                          unsigned int* __restrict__ Y,
                                          int nrows, int bid, short* Ws) {
    int t = threadIdx.x;
#pragma unroll
    for (int i = 0; i < 8; ++i) {
        int c = i * 256 + t;
        int n = c >> 4, q = c & 15;
        uint4 v = *(const uint4*)&Wt[(size_t)n * 128 + q * 8];
        *(uint4*)&Ws[n * 128 + ((q ^ (n & 15)) << 3)] = v;
    }
    __syncthreads();

    int wv = t >> 6;
    int lane = t & 63, l16 = lane & 15, quad = lane >> 4;
    int rbase = bid * BM + wv * 32;

    f32x4 acc[2][8];
#pragma unroll
    for (int rt = 0; rt < 2; ++rt)
#pragma unroll
        for (int nt = 0; nt < 8; ++nt) acc[rt][nt] = (f32x4){0.f, 0.f, 0.f, 0.f};

#pragma unroll
    for (int kb = 0; kb < 4; ++kb) {
        bf16x8 af[2];
#pragma unroll
        for (int rt = 0; rt < 2; ++rt) {
            int row = rbase + rt * 16 + l16;
            if (row > nrows - 1) row = nrows - 1;
            if constexpr (BF16_IN) {
                const unsigned int* Xb = (const unsigned int*)Xv;
                af[rt] = *(const bf16x8*)&Xb[(size_t)row * 64 + kb * 16 + quad * 4];
            } else {
                const float* X = (const float*)Xv;
                float4 fa = ((const float4*)X)[(size_t)row * 32 + kb * 8 + quad * 2];
                float4 fb = ((const float4*)X)[(size_t)row * 32 + kb * 8 + quad * 2 + 1];
                union { uint4 u; bf16x8 v; } cv;
                cv.u.x = bf16pack(fa.x, fa.y);
                cv.u.y = bf16pack(fa.z, fa.w);
                cv.u.z = bf16pack(fb.x, fb.y);
                cv.u.w = bf16pack(fb.z, fb.w);
                af[rt] = cv.v;
            }
        }
        bf16x8 bfr[8];
#pragma unroll
        for (int nt = 0; nt < 8; ++nt) {
            int n = nt * 16 + l16;
            bfr[nt] = *(const bf16x8*)&Ws[n * 128 + (((kb * 4 + quad) ^ l16) << 3)];
        }
#pragma unroll
        for (int rt = 0; rt < 2; ++rt)
#pragma unroll
            for (int nt = 0; nt < 8; ++nt)
                acc[rt][nt] = __builtin_amdgcn_mfma_f32_16x16x32_bf16(
                    af[rt], bfr[nt], acc[rt][nt], 0, 0, 0);
    }

    short* Ys = (short*)Y;
#pragma unroll
    for (int rt = 0; rt < 2; ++rt)
#pragma unroll
        for (int reg = 0; reg < 4; ++reg) {
            int row = rbase + rt * 16 + quad * 4 + reg;
            if (row < nrows) {
#pragma unroll
                for (int nt = 0; nt < 8; ++nt)
                    Ys[(size_t)row * 128 + nt * 16 + l16] = (short)f2bf(acc[rt][nt][reg]);
            }
        }
}

// standalone GEMM (fallback layer 2, bf16 input)
__global__ __launch_bounds__(256) void gemm128_mfma_bf16(const unsigned int* __restrict__ Xb,
                                                         const unsigned short* __restrict__ Wt,
                                                         unsigned int* __restrict__ Y,
                                                         int nrows) {
    __shared__ __align__(16) short Ws[128 * 128];
    gemm_body<true>(Xb, Wt, Y, nrows, blockIdx.x, Ws);
}

// ---------------- L1: {gemm1 (f32 input) || pass2 fine sort} ----------------
__global__ __launch_bounds__(256) void fused_gemm1_pass2(
    const float* __restrict__ feat, const unsigned short* __restrict__ wt1,
    unsigned int* __restrict__ Hb,
    const unsigned int* __restrict__ temp, const int* __restrict__ bofs,
    int* __restrict__ row_ptr, float* __restrict__ dinv,
    int* __restrict__ packed) {
    __shared__ __align__(16) short Ws[128 * 128];  // gemm tile / pass2 union
    int b = blockIdx.x, t = threadIdx.x;
    if (b < G_GEMM) {
        gemm_body<false>(feat, wt1, Hb, N_NODES, b, Ws);
        return;
    }
    int k = b - G_GEMM;
    unsigned int* ed = (unsigned int*)Ws;  // BCAP u32 (8 KB)
    int* hist = (int*)(ed + BCAP);         // 128
    int* rp = hist + 128;                  // 128
    int* cur = rp + 128;                   // 128
    int* sc2 = cur + 128;                  // 128
    int* red = sc2 + 128;                  // 256
    int* sc = red + 256;                   // 256

    int s_t = 0, len = 0;
    if (t < P1_BLOCKS) {
        s_t = bofs[t * (NB + 1) + k];
        len = bofs[t * (NB + 1) + k + 1] - s_t;
    }
    // gbase = sum_b s_b
    red[t] = s_t;
    __syncthreads();
    for (int off = 128; off > 0; off >>= 1) {
        if (t < off) red[t] += red[t + off];
        __syncthreads();
    }
    int gbase = red[0];
    __syncthreads();
    // dloc: exclusive scan of segment lengths
    sc[t] = len;
    __syncthreads();
    for (int off = 1; off < 256; off <<= 1) {
        int a = (t >= off) ? sc[t - off] : 0;
        __syncthreads();
        sc[t] += a;
        __syncthreads();
    }
    int dloc = sc[t] - len;
    int nk = sc[255];
    if (nk > BCAP) nk = BCAP;

    if (t < 128) { hist[t] = 0; cur[t] = 0; }
    __syncthreads();
    // gather segments into LDS
    for (int i = 0; i < len; ++i) {
        int d = dloc + i;
        if (d < BCAP) ed[d] = temp[(size_t)t * 4096 + s_t + i];
    }
    __syncthreads();
    for (int i = t; i < nk; i += 256) atomicAdd(&hist[ed[i] >> 17], 1);
    __syncthreads();

    // exclusive scan over 128 bins
    if (t < 128) sc2[t] = hist[t];
    __syncthreads();
    for (int off = 1; off < 128; off <<= 1) {
        int a = (t < 128 && t >= off) ? sc2[t - off] : 0;
        __syncthreads();
        if (t < 128) sc2[t] += a;
        __syncthreads();
    }
    if (t < 128) {
        rp[t] = sc2[t] - hist[t];
        int n = k * 128 + t;
        if (n < N_NODES) {
            row_ptr[n] = gbase + rp[t];
            dinv[n] = rsqrtf((float)(hist[t] + 1));  // +1 self-loop
        }
    }
    if (k == NB - 1 && t == 0) row_ptr[N_NODES] = N_EDGES;
    __syncthreads();

    for (int i = t; i < nk; i += 256) {
        unsigned int v = ed[i];
        int dl = v >> 17;
        int r = atomicAdd(&cur[dl], 1);
        packed[gbase + rp[dl] + r] = (int)(v & 0x1FFFF);
    }
}

// ---------------- aggregate body (vb-parameterized) -------------------------
// packed = src only (4B/edge). x[v] = dv*(dv*H[v] + sum_s dinv[s]*H[s]) + b.
template <bool RELU>
__device__ __forceinline__ void agg_dev(int vb, const unsigned int* __restrict__ Hb,
                                        const int* __restrict__ packed,
                                        const int* __restrict__ row_ptr,
                                        const float* __restrict__ dinv,
                                        const float* __restrict__ bias,
                                        unsigned int* __restrict__ Xb) {
    int v0 = vb * 8 + (threadIdx.x >> 6) * 2;
    int v1 = v0 + 1;
    int lane = threadIdx.x & 63;
    if (v0 >= N_NODES) return;  // no barriers below: safe in device fn
    bool h1 = (v1 < N_NODES);

    int st0 = row_ptr[v0], en0 = row_ptr[v0 + 1];
    int st1 = h1 ? row_ptr[v1] : 0, en1 = h1 ? row_ptr[v1 + 1] : 0;
    float dv0 = dinv[v0];
    float dv1 = h1 ? dinv[v1] : 0.f;

    unsigned int su0 = Hb[(size_t)v0 * 64 + lane];
    float a0 = dv0 * bflo(su0), a1 = dv0 * bfhi(su0);
    unsigned int su1 = h1 ? Hb[(size_t)v1 * 64 + lane] : 0u;
    float b0 = dv1 * bflo(su1), b1 = dv1 * bfhi(su1);

    // meta prefetch for first chunk
    int p = 0;
    if (lane < 32) {
        if (st0 + lane < en0) p = packed[st0 + lane];
    } else {
        if (st1 + lane - 32 < en1) p = packed[st1 + lane - 32];
    }

    for (int c0 = st0, c1 = st1; c0 < en0 || c1 < en1; c0 += 32, c1 += 32) {
        int n0 = en0 - c0; n0 = n0 < 0 ? 0 : (n0 > 32 ? 32 : n0);
        int n1 = en1 - c1; n1 = n1 < 0 ? 0 : (n1 > 32 ? 32 : n1);
        bool act = (lane < 32) ? (lane < n0) : (lane - 32 < n1);
        float dld = dinv[p];          // p=0 for inactive lanes: safe addr
        float d = act ? dld : 0.f;    // masked after load

        int nmax = n0 > n1 ? n0 : n1;
        int pn = 0;
        bool pref = false;
        for (int j = 0; j < nmax; j += 8) {
            int sA[8], sB[8];
#pragma unroll
            for (int q = 0; q < 8; ++q) {
                sA[q] = __shfl(p, j + q);
                sB[q] = __shfl(p, 32 + j + q);
            }
            unsigned int uA[8], uB[8];
#pragma unroll
            for (int q = 0; q < 8; ++q) {
                uA[q] = Hb[(size_t)sA[q] * 64 + lane];
                uB[q] = Hb[(size_t)sB[q] * 64 + lane];
            }
            if (!pref) {  // prefetch next-chunk meta under the first gathers
                pref = true;
                if (lane < 32) {
                    if (c0 + 32 + lane < en0) pn = packed[c0 + 32 + lane];
                } else {
                    if (c1 + lane < en1) pn = packed[c1 + lane];
                }
            }
            float dA[8], dB[8];
#pragma unroll
            for (int q = 0; q < 8; ++q) {
                dA[q] = __shfl(d, j + q);
                dB[q] = __shfl(d, 32 + j + q);
            }
#pragma unroll
            for (int q = 0; q < 8; ++q) {
                a0 = fmaf(dA[q], bflo(uA[q]), a0);
                a1 = fmaf(dA[q], bfhi(uA[q]), a1);
                b0 = fmaf(dB[q], bflo(uB[q]), b0);
                b1 = fmaf(dB[q], bfhi(uB[q]), b1);
            }
        }
        p = pn;
    }

    float2 bb = ((const float2*)bias)[lane];
    a0 = fmaf(a0, dv0, bb.x);
    a1 = fmaf(a1, dv0, bb.y);
    b0 = fmaf(b0, dv1, bb.x);
    b1 = fmaf(b1, dv1, bb.y);
    if (RELU) {
        a0 = fmaxf(a0, 0.f);
        a1 = fmaxf(a1, 0.f);
        b0 = fmaxf(b0, 0.f);
        b1 = fmaxf(b1, 0.f);
    }
    Xb[(size_t)v0 * 64 + lane] = bf16pack(a0, a1);
    if (h1) Xb[(size_t)v1 * 64 + lane] = bf16pack(b0, b1);
}

// fallback wrapper
template <bool RELU>
__global__ __launch_bounds__(256) void aggregate(const unsigned int* __restrict__ Hb,
                                                 const int* __restrict__ packed,
                                                 const int* __restrict__ row_ptr,
                                                 const float* __restrict__ dinv,
                                                 const float* __restrict__ bias,
                                                 unsigned int* __restrict__ Xb) {
    agg_dev<RELU>(blockIdx.x, Hb, packed, row_ptr, dinv, bias, Xb);
}

// ---------------- score body (vb-parameterized) -----------------------------
__device__ __forceinline__ void score_dev(int vb, const int* __restrict__ ea,
                                          const int* __restrict__ eb,
                                          const unsigned int* __restrict__ Xb,
                                          float* __restrict__ out) {
    int wbase = (vb * 4 + (threadIdx.x >> 6)) * 4;
    int lane = threadIdx.x & 63;
    if (wbase >= N_LABEL) return;  // no barriers: safe
    int ne = N_LABEL - wbase;
    if (ne > 4) ne = 4;

    unsigned int ua[4], ub[4];
#pragma unroll
    for (int e = 0; e < 4; ++e)
        if (e < ne) {
            int ia = ea[wbase + e], ib = eb[wbase + e];
            ua[e] = Xb[(size_t)ia * 64 + lane];
            ub[e] = Xb[(size_t)ib * 64 + lane];
        }
#pragma unroll
    for (int e = 0; e < 4; ++e)
        if (e < ne) {
            float p = bflo(ua[e]) * bflo(ub[e]) + bfhi(ua[e]) * bfhi(ub[e]);
#pragma unroll
            for (int off = 32; off > 0; off >>= 1) p += __shfl_down(p, off);
            if (lane == 0) out[wbase + e] = p;
        }
}

// fallback wrapper
__global__ __launch_bounds__(256) void score_kernel(const int* __restrict__ ea,
                                                    const int* __restrict__ eb,
                                                    const unsigned int* __restrict__ Xb,
                                                    float* __restrict__ out) {
    score_dev(blockIdx.x, ea, eb, Xb, out);
}

// ---------------- gemm2 column-half tile (16KB LDS, acc 32 regs) ------------
__device__ __forceinline__ void gemm2half_dev(int vb, const unsigned int* __restrict__ Xb,
                                              const unsigned short* __restrict__ Wt,
                                              unsigned int* __restrict__ Y, short* Ws) {
    int bid = vb >> 1, h = vb & 1;
    int t = threadIdx.x;
#pragma unroll
    for (int i = 0; i < 4; ++i) {
        int c = i * 256 + t;        // 0..1023
        int n = c >> 4, q = c & 15; // n 0..63
        uint4 v = *(const uint4*)&Wt[(size_t)(h * 64 + n) * 128 + q * 8];
        *(uint4*)&Ws[n * 128 + ((q ^ (n & 15)) << 3)] = v;
    }
    __syncthreads();

    int wv = t >> 6;
    int lane = t & 63, l16 = lane & 15, quad = lane >> 4;
    int rbase = bid * BM + wv * 32;

    f32x4 acc[2][4];
#pragma unroll
    for (int rt = 0; rt < 2; ++rt)
#pragma unroll
        for (int nt = 0; nt < 4; ++nt) acc[rt][nt] = (f32x4){0.f, 0.f, 0.f, 0.f};

#pragma unroll
    for (int kb = 0; kb < 4; ++kb) {
        bf16x8 af[2];
#pragma unroll
        for (int rt = 0; rt < 2; ++rt) {
            int row = rbase + rt * 16 + l16;
            if (row > N_NODES - 1) row = N_NODES - 1;
            af[rt] = *(const bf16x8*)&Xb[(size_t)row * 64 + kb * 16 + quad * 4];
        }
        bf16x8 bfr[4];
#pragma unroll
        for (int nt = 0; nt < 4; ++nt) {
            int n = nt * 16 + l16;
            bfr[nt] = *(const bf16x8*)&Ws[n * 128 + (((kb * 4 + quad) ^ l16) << 3)];
        }
#pragma unroll
        for (int rt = 0; rt < 2; ++rt)
#pragma unroll
            for (int nt = 0; nt < 4; ++nt)
                acc[rt][nt] = __builtin_amdgcn_mfma_f32_16x16x32_bf16(
                    af[rt], bfr[nt], acc[rt][nt], 0, 0, 0);
    }
    __syncthreads();  // Ws reused by next vb iteration

    short* Ys = (short*)Y;
#pragma unroll
    for (int rt = 0; rt < 2; ++rt)
#pragma unroll
        for (int reg = 0; reg < 4; ++reg) {
            int row = rbase + rt * 16 + quad * 4 + reg;
            if (row < N_NODES) {
#pragma unroll
                for (int nt = 0; nt < 4; ++nt)
                    Ys[(size_t)row * 128 + h * 64 + nt * 16 + l16] =
                        (short)f2bf(acc[rt][nt][reg]);
            }
        }
}

// ---------------- cooperative tail: agg1 -> gemm2 -> agg2 -> score ----------
// Plain launch_bounds(256): allocator free to use ~70-90 VGPR (NO spill).
__global__ __launch_bounds__(256) void tail_coop(
    unsigned int* __restrict__ Hb, const int* __restrict__ packed,
    const int* __restrict__ row_ptr, const float* __restrict__ dinv,
    const float* __restrict__ b1, unsigned int* __restrict__ Xb,
    const unsigned short* __restrict__ wt2, const float* __restrict__ b2,
    const int* __restrict__ la, const int* __restrict__ lb,
    float* __restrict__ out) {
    __shared__ __align__(16) short Ws[64 * 128];  // 16 KB (gemm2 phase only)
    cg::grid_group grid = cg::this_grid();
    int nb = gridDim.x;

    for (int vb = blockIdx.x; vb < AGG_VB; vb += nb)
        agg_dev<true>(vb, Hb, packed, row_ptr, dinv, b1, Xb);
    grid.sync();
    for (int vb = blockIdx.x; vb < 2 * G_GEMM; vb += nb)
        gemm2half_dev(vb, Xb, wt2, Hb, Ws);
    grid.sync();
    for (int vb = blockIdx.x; vb < AGG_VB; vb += nb)
        agg_dev<false>(vb, Hb, packed, row_ptr, dinv, b2, Xb);
    grid.sync();
    for (int vb = blockIdx.x; vb < SCORE_VB; vb += nb)
        score_dev(vb, la, lb, Xb, out);
}

extern "C" void kernel_launch(void* const* d_in, const int* in_sizes, int n_in,
                              void* d_out, int out_size, void* d_ws, size_t ws_size,
                              hipStream_t stream) {
    const float* feat = (const float*)d_in[0];
    const int* ei = (const int*)d_in[1];
    const int* eli = (const int*)d_in[2];
    const float* W1 = (const float*)d_in[3];
    const float* b1 = (const float*)d_in[4];
    const float* W2 = (const float*)d_in[5];
    const float* b2 = (const float*)d_in[6];
    float* out = (float*)d_out;

    const int* src = ei;
    const int* dst = ei + N_EDGES;
    const int* la = eli;
    const int* lb = eli + N_LABEL;

    int* row_ptr = (int*)d_ws;                                // N+4 ints
    float* dinv = (float*)(row_ptr + N_NODES + 4);            // N
    unsigned short* wt1 = (unsigned short*)(dinv + N_NODES);  // 16384 ushort
    unsigned short* wt2 = wt1 + 16384;                        // 16384 ushort
    int* packed = (int*)(wt2 + 16384);                        // E ints (4 MB)
    unsigned int* Hb = (unsigned int*)(packed + N_EDGES);     // N*64 uints
    unsigned int* Xb = Hb + (size_t)N_NODES * 64;             // N*64 uints
    // temp (block-major records, 4 MB) + bofs (245*783 ints) alias Xb
    unsigned int* temp = Xb;
    int* bofs = (int*)(temp + (size_t)P1_BLOCKS * 4096);

    const int TB = 256;
    int gGemm = (N_NODES + BM - 1) / BM;  // 782
    int gAgg = (N_NODES + 7) / 8;         // 12500
    int gScore = (N_LABEL + 15) / 16;     // 12500

    // coop grid: occupancy-query * CU count, static-cached (-1 = disabled)
    static int coop_grid = -2;
    if (coop_grid == -2) {
        int nb = 0;
        hipError_t e1 = hipOccupancyMaxActiveBlocksPerMultiprocessor(&nb, tail_coop, 256, 0);
        if (e1 != hipSuccess || nb < 1) {
            coop_grid = -1;
        } else {
            int dev = 0;
            hipGetDevice(&dev);
            hipDeviceProp_t prop;
            if (hipGetDeviceProperties(&prop, dev) != hipSuccess) {
                coop_grid = -1;
            } else {
                long g = (long)nb * prop.multiProcessorCount;
                coop_grid = (int)(g < AGG_VB ? g : AGG_VB);
            }
        }
    }

    // L0: w2bf || pass1 (both independent of everything)
    w2bf_pass1<<<G_CONV + P1_BLOCKS, TB, 0, stream>>>(W1, W2, wt1, wt2,
                                                      src, dst, temp, bofs);

    // L1: gemm1 || pass2 (gemm1 needs wt1 only; pass2 needs pass1 only)
    fused_gemm1_pass2<<<G_GEMM + NB, TB, 0, stream>>>(
        feat, wt1, Hb, temp, bofs, row_ptr, dinv, packed);

    // L2: cooperative tail {agg1 -> gemm2 -> agg2 -> score}
    bool coop_ok = false;
    if (coop_grid > 0) {
        void* cargs[11] = {(void*)&Hb,     (void*)&packed, (void*)&row_ptr,
                           (void*)&dinv,   (void*)&b1,     (void*)&Xb,
                           (void*)&wt2,    (void*)&b2,     (void*)&la,
                           (void*)&lb,     (void*)&out};
        coop_ok = (hipLaunchCooperativeKernel(tail_coop, dim3(coop_grid), dim3(TB),
                                              cargs, 0, stream) == hipSuccess);
    }
    if (!coop_ok) {
        // fallback: R20's proven 4-launch tail
        aggregate<true><<<gAgg, TB, 0, stream>>>(Hb, packed, row_ptr, dinv, b1, Xb);
        gemm128_mfma_bf16<<<gGemm, TB, 0, stream>>>(Xb, wt2, Hb, N_NODES);
        aggregate<false><<<gAgg, TB, 0, stream>>>(Hb, packed, row_ptr, dinv, b2, Xb);
        score_kernel<<<gScore, TB, 0, stream>>>(la, lb, Xb, out);
    }
}

// Round 11
// 275.156 us; speedup vs baseline: 3.0722x; 2.2014x over previous
//
#include <hip/hip_runtime.h>
#include <hip/hip_bf16.h>

// GCN link-prediction: 2x GCNConv(128->128) + edge dot scoring.
// Round 23: REVERT to R20 (best verified, 275.8us). R21/R22 coop-tail
// experiments both regressed (R21: launch_bounds VGPR cap -> spill, 845us;
// R22: no spill, normal traffic, but uniform 3x per-wave slowdown across
// all phases under hipLaunchCooperativeKernel -> 605us). Coop fusion is
// REFUTED on gfx950 for this workload: grid.sync's cross-XCD coherence
// cost exceeds the ~10-15us of launch gaps it removes.
// LESSONS BANKED:
// - coop tail fusion: refuted (R21 spill; R22 3x issue-rate degradation).
// - NEVER set launch_bounds min-waves on kernels whose hot phase needs
//   register-resident MLP state; spill turns 78MB writes into 383MB (R21).
// - aggregate gather: pinned at ~3.65 TB/s random-64B fabric floor; FETCH
//   181MB invariant (graph-structural); micro-tuning is noise (R17).
// - never fuse latency-bound gather with reg/LDS-heavy MFMA (R10).
// - never read MFMA B-frags strided from global, incl. staging (R11/R16).
// - partial-line scatter = write-allocate amplification (R13, R18).
// - CSR via LDS counting sort >> 1M global atomics (R14: -57us).
// - launch gap ~2-4us each: minimize dispatch count (R18/R19/R20).

#define N_NODES 100000
#define N_EDGES 1000000
#define N_LABEL 200000
#define D_FEAT 128
#define BM 128

#define NB 782        // coarse buckets: ceil(100000/128) nodes each
#define BCAP 2048     // pass2 LDS capacity per bucket (mean 1279, +6sig ~1500)
#define P1_EPT 16     // pass1 edges per thread
#define P1_BLOCKS 245 // ceil(1e6/4096)
#define G_GEMM 782    // ceil(100000/128)
#define G_CONV 128    // W1+W2 conversion blocks (32768 elems / 256)

typedef short bf16x8 __attribute__((ext_vector_type(8)));
typedef float f32x4 __attribute__((ext_vector_type(4)));

// ---- bf16 helpers (RNE) ----
__device__ inline unsigned int f2bf(float x) {
    unsigned int u = __float_as_uint(x);
    return (u + 0x7FFFu + ((u >> 16) & 1u)) >> 16;
}
__device__ inline unsigned int bf16pack(float a, float b) {
    return f2bf(a) | (f2bf(b) << 16);
}
__device__ inline float bflo(unsigned int u) { return __uint_as_float(u << 16); }
__device__ inline float bfhi(unsigned int u) { return __uint_as_float(u & 0xFFFF0000u); }

// ---------------- L0: {w2bf || pass1 (scatter-free)} ------------------------
// blocks [0,G_CONV): W->bf16 transpose. blocks [G_CONV, G_CONV+P1_BLOCKS):
// pass1 block b sorts its 4096 edges by bucket in LDS, dumps block-major
// temp[b*4096] coalesced + bofs[b][0..782]. No global atomics.
__global__ __launch_bounds__(256) void w2bf_pass1(
    const float* __restrict__ W1, const float* __restrict__ W2,
    unsigned short* __restrict__ Wt1, unsigned short* __restrict__ Wt2,
    const int* __restrict__ src, const int* __restrict__ dst,
    unsigned int* __restrict__ temp, int* __restrict__ bofs) {
    __shared__ __align__(16) unsigned int S[4096 + 1024 + 256];  // 21.5 KB
    int b = blockIdx.x, t = threadIdx.x;
    if (b < G_CONV) {
        int i = b * 256 + t;  // 0..32767
        const float* W = (i < 16384) ? W1 : W2;
        unsigned short* Wt = (i < 16384) ? Wt1 : Wt2;
        int j = i & 16383;
        int n = j >> 7, k = j & 127;
        Wt[j] = (unsigned short)f2bf(W[(size_t)k * 128 + n]);
        return;
    }
    b -= G_CONV;
    unsigned int* ed16 = S;            // 4096 u32 (16 KB)
    int* hist = (int*)(ed16 + 4096);   // 1024 ints (bins padded)
    int* red = hist + 1024;            // 256

    for (int i = t; i < 1024; i += 256) hist[i] = 0;
    __syncthreads();

    int se[P1_EPT], de[P1_EPT], rk[P1_EPT];
    int e0 = b * 4096 + t;
#pragma unroll
    for (int j = 0; j < P1_EPT; ++j) {
        int e = e0 + j * 256;
        if (e < N_EDGES) {
            se[j] = src[e];
            de[j] = dst[e];
            rk[j] = atomicAdd(&hist[de[j] >> 7], 1);
        }
    }
    __syncthreads();

    // exclusive scan over 1024 bins: thread t owns bins 4t..4t+3
    int c0 = hist[4 * t], c1 = hist[4 * t + 1], c2 = hist[4 * t + 2], c3 = hist[4 * t + 3];
    int s = c0 + c1 + c2 + c3;
    red[t] = s;
    __syncthreads();
    for (int off = 1; off < 256; off <<= 1) {
        int a = (t >= off) ? red[t - off] : 0;
        __syncthreads();
        red[t] += a;
        __syncthreads();
    }
    int excl = red[t] - s;
    hist[4 * t] = excl;
    hist[4 * t + 1] = excl + c0;
    hist[4 * t + 2] = excl + c0 + c1;
    hist[4 * t + 3] = excl + c0 + c1 + c2;
    __syncthreads();

    // scatter records into LDS (bucket-sorted within block)
#pragma unroll
    for (int j = 0; j < P1_EPT; ++j) {
        int e = e0 + j * 256;
        if (e < N_EDGES) {
            int pos = hist[de[j] >> 7] + rk[j];
            ed16[pos] = (unsigned int)(((de[j] & 127) << 17) | se[j]);
        }
    }
    __syncthreads();

    // coalesced dump + bofs
#pragma unroll
    for (int i = 0; i < 4; ++i)
        ((uint4*)temp)[(size_t)b * 1024 + i * 256 + t] = ((uint4*)ed16)[i * 256 + t];
    for (int j = t; j < NB; j += 256) bofs[b * (NB + 1) + j] = hist[j];
    if (t == 0) {
        int cnt = N_EDGES - b * 4096;
        if (cnt > 4096) cnt = 4096;
        bofs[b * (NB + 1) + NB] = cnt;
    }
}

// ---------------- MFMA GEMM body, LDS-staged bf16 W ----------------
template <bool BF16_IN>
__device__ __forceinline__ void gemm_body(const void* __restrict__ Xv,
                                          const unsigned short* __restrict__ Wt,
                                          unsigned int* __restrict__ Y,
                                          int nrows, int bid, short* Ws) {
    int t = threadIdx.x;
#pragma unroll
    for (int i = 0; i < 8; ++i) {
        int c = i * 256 + t;
        int n = c >> 4, q = c & 15;
        uint4 v = *(const uint4*)&Wt[(size_t)n * 128 + q * 8];
        *(uint4*)&Ws[n * 128 + ((q ^ (n & 15)) << 3)] = v;
    }
    __syncthreads();

    int wv = t >> 6;
    int lane = t & 63, l16 = lane & 15, quad = lane >> 4;
    int rbase = bid * BM + wv * 32;

    f32x4 acc[2][8];
#pragma unroll
    for (int rt = 0; rt < 2; ++rt)
#pragma unroll
        for (int nt = 0; nt < 8; ++nt) acc[rt][nt] = (f32x4){0.f, 0.f, 0.f, 0.f};

#pragma unroll
    for (int kb = 0; kb < 4; ++kb) {
        bf16x8 af[2];
#pragma unroll
        for (int rt = 0; rt < 2; ++rt) {
            int row = rbase + rt * 16 + l16;
            if (row > nrows - 1) row = nrows - 1;
            if constexpr (BF16_IN) {
                const unsigned int* Xb = (const unsigned int*)Xv;
                af[rt] = *(const bf16x8*)&Xb[(size_t)row * 64 + kb * 16 + quad * 4];
            } else {
                const float* X = (const float*)Xv;
                float4 fa = ((const float4*)X)[(size_t)row * 32 + kb * 8 + quad * 2];
                float4 fb = ((const float4*)X)[(size_t)row * 32 + kb * 8 + quad * 2 + 1];
                union { uint4 u; bf16x8 v; } cv;
                cv.u.x = bf16pack(fa.x, fa.y);
                cv.u.y = bf16pack(fa.z, fa.w);
                cv.u.z = bf16pack(fb.x, fb.y);
                cv.u.w = bf16pack(fb.z, fb.w);
                af[rt] = cv.v;
            }
        }
        bf16x8 bfr[8];
#pragma unroll
        for (int nt = 0; nt < 8; ++nt) {
            int n = nt * 16 + l16;
            bfr[nt] = *(const bf16x8*)&Ws[n * 128 + (((kb * 4 + quad) ^ l16) << 3)];
        }
#pragma unroll
        for (int rt = 0; rt < 2; ++rt)
#pragma unroll
            for (int nt = 0; nt < 8; ++nt)
                acc[rt][nt] = __builtin_amdgcn_mfma_f32_16x16x32_bf16(
                    af[rt], bfr[nt], acc[rt][nt], 0, 0, 0);
    }

    short* Ys = (short*)Y;
#pragma unroll
    for (int rt = 0; rt < 2; ++rt)
#pragma unroll
        for (int reg = 0; reg < 4; ++reg) {
            int row = rbase + rt * 16 + quad * 4 + reg;
            if (row < nrows) {
#pragma unroll
                for (int nt = 0; nt < 8; ++nt)
                    Ys[(size_t)row * 128 + nt * 16 + l16] = (short)f2bf(acc[rt][nt][reg]);
            }
        }
}

// standalone GEMM (layer 2, bf16 input)
__global__ __launch_bounds__(256) void gemm128_mfma_bf16(const unsigned int* __restrict__ Xb,
                                                         const unsigned short* __restrict__ Wt,
                                                         unsigned int* __restrict__ Y,
                                                         int nrows) {
    __shared__ __align__(16) short Ws[128 * 128];
    gemm_body<true>(Xb, Wt, Y, nrows, blockIdx.x, Ws);
}

// ---------------- L1: {gemm1 (f32 input) || pass2 fine sort} ----------------
// pass2 block k: gather its 245 segments from block-major temp (L2/L3-hot),
// gbase = sum_b bofs[b][k], LDS fine counting sort, contiguous packed write.
// pass2's ~12.5KB lives inside gemm's 32KB Ws union.
__global__ __launch_bounds__(256) void fused_gemm1_pass2(
    const float* __restrict__ feat, const unsigned short* __restrict__ wt1,
    unsigned int* __restrict__ Hb,
    const unsigned int* __restrict__ temp, const int* __restrict__ bofs,
    int* __restrict__ row_ptr, float* __restrict__ dinv,
    int* __restrict__ packed) {
    __shared__ __align__(16) short Ws[128 * 128];  // gemm tile / pass2 union
    int b = blockIdx.x, t = threadIdx.x;
    if (b < G_GEMM) {
        gemm_body<false>(feat, wt1, Hb, N_NODES, b, Ws);
        return;
    }
    int k = b - G_GEMM;
    unsigned int* ed = (unsigned int*)Ws;  // BCAP u32 (8 KB)
    int* hist = (int*)(ed + BCAP);         // 128
    int* rp = hist + 128;                  // 128
    int* cur = rp + 128;                   // 128
    int* sc2 = cur + 128;                  // 128
    int* red = sc2 + 128;                  // 256
    int* sc = red + 256;                   // 256

    int s_t = 0, len = 0;
    if (t < P1_BLOCKS) {
        s_t = bofs[t * (NB + 1) + k];
        len = bofs[t * (NB + 1) + k + 1] - s_t;
    }
    // gbase = sum_b s_b
    red[t] = s_t;
    __syncthreads();
    for (int off = 128; off > 0; off >>= 1) {
        if (t < off) red[t] += red[t + off];
        __syncthreads();
    }
    int gbase = red[0];
    __syncthreads();
    // dloc: exclusive scan of segment lengths
    sc[t] = len;
    __syncthreads();
    for (int off = 1; off < 256; off <<= 1) {
        int a = (t >= off) ? sc[t - off] : 0;
        __syncthreads();
        sc[t] += a;
        __syncthreads();
    }
    int dloc = sc[t] - len;
    int nk = sc[255];
    if (nk > BCAP) nk = BCAP;

    if (t < 128) { hist[t] = 0; cur[t] = 0; }
    __syncthreads();
    // gather segments into LDS
    for (int i = 0; i < len; ++i) {
        int d = dloc + i;
        if (d < BCAP) ed[d] = temp[(size_t)t * 4096 + s_t + i];
    }
    __syncthreads();
    for (int i = t; i < nk; i += 256) atomicAdd(&hist[ed[i] >> 17], 1);
    __syncthreads();

    // exclusive scan over 128 bins
    if (t < 128) sc2[t] = hist[t];
    __syncthreads();
    for (int off = 1; off < 128; off <<= 1) {
        int a = (t < 128 && t >= off) ? sc2[t - off] : 0;
        __syncthreads();
        if (t < 128) sc2[t] += a;
        __syncthreads();
    }
    if (t < 128) {
        rp[t] = sc2[t] - hist[t];
        int n = k * 128 + t;
        if (n < N_NODES) {
            row_ptr[n] = gbase + rp[t];
            dinv[n] = rsqrtf((float)(hist[t] + 1));  // +1 self-loop
        }
    }
    if (k == NB - 1 && t == 0) row_ptr[N_NODES] = N_EDGES;
    __syncthreads();

    for (int i = t; i < nk; i += 256) {
        unsigned int v = ed[i];
        int dl = v >> 17;
        int r = atomicAdd(&cur[dl], 1);
        packed[gbase + rp[dl] + r] = (int)(v & 0x1FFFF);
    }
}

// ---------------- gather-aggregate: 2 nodes/wave, 16 gathers in flight ----
// packed = src only (4B/edge). x[v] = dv*(dv*H[v] + sum_s dinv[s]*H[s]) + b.
template <bool RELU>
__global__ __launch_bounds__(256) void aggregate(const unsigned int* __restrict__ Hb,
                                                 const int* __restrict__ packed,
                                                 const int* __restrict__ row_ptr,
                                                 const float* __restrict__ dinv,
                                                 const float* __restrict__ bias,
                                                 unsigned int* __restrict__ Xb) {
    int v0 = blockIdx.x * 8 + (threadIdx.x >> 6) * 2;
    int v1 = v0 + 1;
    int lane = threadIdx.x & 63;
    if (v0 >= N_NODES) return;
    bool h1 = (v1 < N_NODES);

    int st0 = row_ptr[v0], en0 = row_ptr[v0 + 1];
    int st1 = h1 ? row_ptr[v1] : 0, en1 = h1 ? row_ptr[v1 + 1] : 0;
    float dv0 = dinv[v0];
    float dv1 = h1 ? dinv[v1] : 0.f;

    unsigned int su0 = Hb[(size_t)v0 * 64 + lane];
    float a0 = dv0 * bflo(su0), a1 = dv0 * bfhi(su0);
    unsigned int su1 = h1 ? Hb[(size_t)v1 * 64 + lane] : 0u;
    float b0 = dv1 * bflo(su1), b1 = dv1 * bfhi(su1);

    // meta prefetch for first chunk
    int p = 0;
    if (lane < 32) {
        if (st0 + lane < en0) p = packed[st0 + lane];
    } else {
        if (st1 + lane - 32 < en1) p = packed[st1 + lane - 32];
    }

    for (int c0 = st0, c1 = st1; c0 < en0 || c1 < en1; c0 += 32, c1 += 32) {
        int n0 = en0 - c0; n0 = n0 < 0 ? 0 : (n0 > 32 ? 32 : n0);
        int n1 = en1 - c1; n1 = n1 < 0 ? 0 : (n1 > 32 ? 32 : n1);
        bool act = (lane < 32) ? (lane < n0) : (lane - 32 < n1);
        float dld = dinv[p];          // p=0 for inactive lanes: safe addr
        float d = act ? dld : 0.f;    // masked after load

        int nmax = n0 > n1 ? n0 : n1;
        int pn = 0;
        bool pref = false;
        for (int j = 0; j < nmax; j += 8) {
            int sA[8], sB[8];
#pragma unroll
            for (int q = 0; q < 8; ++q) {
                sA[q] = __shfl(p, j + q);
                sB[q] = __shfl(p, 32 + j + q);
            }
            unsigned int uA[8], uB[8];
#pragma unroll
            for (int q = 0; q < 8; ++q) {
                uA[q] = Hb[(size_t)sA[q] * 64 + lane];
                uB[q] = Hb[(size_t)sB[q] * 64 + lane];
            }
            if (!pref) {  // prefetch next-chunk meta under the first gathers
                pref = true;
                if (lane < 32) {
                    if (c0 + 32 + lane < en0) pn = packed[c0 + 32 + lane];
                } else {
                    if (c1 + lane < en1) pn = packed[c1 + lane];
                }
            }
            float dA[8], dB[8];
#pragma unroll
            for (int q = 0; q < 8; ++q) {
                dA[q] = __shfl(d, j + q);
                dB[q] = __shfl(d, 32 + j + q);
            }
#pragma unroll
            for (int q = 0; q < 8; ++q) {
                a0 = fmaf(dA[q], bflo(uA[q]), a0);
                a1 = fmaf(dA[q], bfhi(uA[q]), a1);
                b0 = fmaf(dB[q], bflo(uB[q]), b0);
                b1 = fmaf(dB[q], bfhi(uB[q]), b1);
            }
        }
        p = pn;
    }

    float2 bb = ((const float2*)bias)[lane];
    a0 = fmaf(a0, dv0, bb.x);
    a1 = fmaf(a1, dv0, bb.y);
    b0 = fmaf(b0, dv1, bb.x);
    b1 = fmaf(b1, dv1, bb.y);
    if (RELU) {
        a0 = fmaxf(a0, 0.f);
        a1 = fmaxf(a1, 0.f);
        b0 = fmaxf(b0, 0.f);
        b1 = fmaxf(b1, 0.f);
    }
    Xb[(size_t)v0 * 64 + lane] = bf16pack(a0, a1);
    if (h1) Xb[(size_t)v1 * 64 + lane] = bf16pack(b0, b1);
}

// ---------------- edge scoring: 4 label edges per wave (bias pre-folded) ----
__global__ __launch_bounds__(256) void score_kernel(const int* __restrict__ ea,
                                                    const int* __restrict__ eb,
                                                    const unsigned int* __restrict__ Xb,
                                                    float* __restrict__ out) {
    int wbase = (blockIdx.x * 4 + (threadIdx.x >> 6)) * 4;
    int lane = threadIdx.x & 63;
    if (wbase >= N_LABEL) return;
    int ne = N_LABEL - wbase;
    if (ne > 4) ne = 4;

    unsigned int ua[4], ub[4];
#pragma unroll
    for (int e = 0; e < 4; ++e)
        if (e < ne) {
            int ia = ea[wbase + e], ib = eb[wbase + e];
            ua[e] = Xb[(size_t)ia * 64 + lane];
            ub[e] = Xb[(size_t)ib * 64 + lane];
        }
#pragma unroll
    for (int e = 0; e < 4; ++e)
        if (e < ne) {
            float p = bflo(ua[e]) * bflo(ub[e]) + bfhi(ua[e]) * bfhi(ub[e]);
#pragma unroll
            for (int off = 32; off > 0; off >>= 1) p += __shfl_down(p, off);
            if (lane == 0) out[wbase + e] = p;
        }
}

extern "C" void kernel_launch(void* const* d_in, const int* in_sizes, int n_in,
                              void* d_out, int out_size, void* d_ws, size_t ws_size,
                              hipStream_t stream) {
    const float* feat = (const float*)d_in[0];
    const int* ei = (const int*)d_in[1];
    const int* eli = (const int*)d_in[2];
    const float* W1 = (const float*)d_in[3];
    const float* b1 = (const float*)d_in[4];
    const float* W2 = (const float*)d_in[5];
    const float* b2 = (const float*)d_in[6];
    float* out = (float*)d_out;

    const int* src = ei;
    const int* dst = ei + N_EDGES;
    const int* la = eli;
    const int* lb = eli + N_LABEL;

    int* row_ptr = (int*)d_ws;                                // N+4 ints
    float* dinv = (float*)(row_ptr + N_NODES + 4);            // N
    unsigned short* wt1 = (unsigned short*)(dinv + N_NODES);  // 16384 ushort
    unsigned short* wt2 = wt1 + 16384;                        // 16384 ushort
    int* packed = (int*)(wt2 + 16384);                        // E ints (4 MB)
    unsigned int* Hb = (unsigned int*)(packed + N_EDGES);     // N*64 uints
    unsigned int* Xb = Hb + (size_t)N_NODES * 64;             // N*64 uints
    // temp (block-major records, 4 MB) + bofs (245*783 ints) alias Xb
    unsigned int* temp = Xb;
    int* bofs = (int*)(temp + (size_t)P1_BLOCKS * 4096);

    const int TB = 256;
    int gGemm = (N_NODES + BM - 1) / BM;  // 782
    int gAgg = (N_NODES + 7) / 8;         // 12500
    int gScore = (N_LABEL + 15) / 16;     // 12500

    // L0: w2bf || pass1 (both independent of everything)
    w2bf_pass1<<<G_CONV + P1_BLOCKS, TB, 0, stream>>>(W1, W2, wt1, wt2,
                                                      src, dst, temp, bofs);

    // L1: gemm1 || pass2 (gemm1 needs wt1 only; pass2 needs pass1 only)
    fused_gemm1_pass2<<<G_GEMM + NB, TB, 0, stream>>>(
        feat, wt1, Hb, temp, bofs, row_ptr, dinv, packed);

    // layer 1 aggregate
    aggregate<true><<<gAgg, TB, 0, stream>>>(Hb, packed, row_ptr, dinv, b1, Xb);

    // layer 2
    gemm128_mfma_bf16<<<gGemm, TB, 0, stream>>>(Xb, wt2, Hb, N_NODES);
    aggregate<false><<<gAgg, TB, 0, stream>>>(Hb, packed, row_ptr, dinv, b2, Xb);

    // scoring (b2 already folded into Xb)
    score_kernel<<<gScore, TB, 0, stream>>>(la, lb, Xb, out);
}